// Round 3
// baseline (90.969 us; speedup 1.0000x reference)
//
#include <hip/hip_runtime.h>
#include <cstddef>

// YOLOv3 loss, MI355X. b=32, scales 13/26/52, 3 anchors, 80 classes, 50 boxes.
// Input order (setup_inputs dict order, interleaved per scale):
//   d_in[4k+0]=output_k (b,255,S,S)  d_in[4k+1]=loc_k (b,3,4,S,S)
//   d_in[4k+2]=cls_k (b,3,80,S,S)    d_in[4k+3]=boxes_k (b,50,4)
// ws: 4 floats {LL, LC, LK, NPOS}
// R2: VW=1 everywhere -> grid 1344 blocks (65% occupancy cap) vs R1's 384 (18.75%).
//     Wave-contiguous lanes keep coalescing; TLP replaces per-thread vector width.

constexpr int NC = 80;
constexpr int NA = 3;
constexpr int NM = 50;
constexpr int NB = 32;

__device__ constexpr float ANCW[3][3] = {{116.f,156.f,373.f},{30.f,62.f,59.f},{10.f,16.f,33.f}};
__device__ constexpr float ANCH[3][3] = {{ 90.f,198.f,326.f},{61.f,45.f,119.f},{13.f,30.f,23.f}};

__device__ __forceinline__ float frcp_(float x) { return __builtin_amdgcn_rcpf(x); }
__device__ __forceinline__ float sigmoidf_(float x) { return frcp_(1.0f + __expf(-x)); }

__global__ void init_acc_kernel(float* acc) {
    if (threadIdx.x < 4) acc[threadIdx.x] = 0.0f;
}

__global__ void finalize_kernel(const float* __restrict__ acc, float* __restrict__ out) {
    out[0] = 5.0f * (acc[0] + acc[1] + acc[2]) / (float)NB / acc[3];
}

template <int SC, int S, bool COUNT_POS>
__device__ __forceinline__ void process_scale(
    const float* __restrict__ outp, const float* __restrict__ locp,
    const float* __restrict__ clsp, const float* __restrict__ boxp,
    float* __restrict__ acc, int rel)
{
    constexpr int SS = S * S;
    constexpr int CELLS = NA * SS;
    constexpr int BPB = (CELLS + 255) / 256;

    const int b   = rel / BPB;
    const int chk = rel % BPB;
    const int tid = threadIdx.x;

    __shared__ float sbx[NM * 4];
    __shared__ float sba[NM];
    __shared__ float red[4][4];

    if (tid < NM * 4) sbx[tid] = boxp[(size_t)b * NM * 4 + tid];
    __syncthreads();
    if (tid < NM)
        sba[tid] = (sbx[tid*4+2] - sbx[tid*4+0]) * (sbx[tid*4+3] - sbx[tid*4+1]);
    __syncthreads();

    float ll = 0.f, lc = 0.f, lk = 0.f, np = 0.f;

    const int cell = chk * 256 + tid;
    if (cell < CELLS) {
        const int a   = cell / SS;
        const int rem = cell - a * SS;

        const float* op = outp + ((size_t)b * NA + a) * (5 + NC) * SS + rem;
        const float* cp = clsp + ((size_t)b * NA + a) * NC * SS + rem;
        const float* lp = locp + ((size_t)b * NA + a) * 4 * SS + rem;

        // ---- class loss: sum_{t>0}(p-t)^2 = A2/Z^2 - 2 A1/Z + A0 ----
        // no max-shift: logits ~N(0,1); exp fits f32 comfortably.
        float Z = 0.f, A2 = 0.f, A1 = 0.f, A0 = 0.f;
        #pragma unroll 8
        for (int c = 0; c < NC; ++c) {
            const float l = op[(size_t)(5 + c) * SS];
            const float t = cp[(size_t)c * SS];
            const float e  = __expf(l);
            const float wf = (t > 0.f) ? 1.f : 0.f;
            const float we = wf * e;
            const float wt = wf * t;
            Z  += e;
            A2  = fmaf(we, e, A2);
            A1  = fmaf(we, t, A1);
            A0  = fmaf(wt, t, A0);
        }

        const float tx = op[0 * SS];
        const float ty = op[1 * SS];
        const float tw = op[2 * SS];
        const float th = op[3 * SS];
        const float tc = op[4 * SS];
        const float l0 = lp[0 * SS], l1 = lp[1 * SS], l2 = lp[2 * SS], l3 = lp[3 * SS];

        const bool pos = A0 > 0.f;
        if (pos) {
            const float d0 = tx-l0, d1 = ty-l1, d2 = tw-l2, d3 = th-l3;
            ll = d0*d0 + d1*d1 + d2*d2 + d3*d3;
            if (COUNT_POS) np = 1.f;
        }

        const float aw = ANCW[SC][a] * ((float)S / 416.f);
        const float ah = ANCH[SC][a] * ((float)S / 416.f);
        const int y = rem / S;
        const int x = rem - y * S;
        const float sx = sigmoidf_(tx) + (float)x;
        const float sy = sigmoidf_(ty) + (float)y;
        const float bw = __expf(tw) * aw;
        const float bh = __expf(th) * ah;
        const float x1 = sx - bw * 0.5f, y1 = sy - bh * 0.5f;
        const float x2 = sx + bw * 0.5f, y2 = sy + bh * 0.5f;
        const float area = (x2 - x1) * (y2 - y1);

        // ---- max IoU vs 50 boxes, rational compare (single rcp at end) ----
        float bn = 0.f, bd = 1.f;
        #pragma unroll 10
        for (int j = 0; j < NM; ++j) {
            const float bx1 = sbx[j*4+0], by1 = sbx[j*4+1];
            const float bx2 = sbx[j*4+2], by2 = sbx[j*4+3];
            const float iw = fmaxf(fminf(x2, bx2) - fmaxf(x1, bx1), 0.f);
            const float ih = fmaxf(fminf(y2, by2) - fmaxf(y1, by1), 0.f);
            const float inter = iw * ih;
            const float uni   = area + sba[j] - inter;
            const bool upd = inter * bd > bn * uni;
            bn = upd ? inter : bn;
            bd = upd ? uni   : bd;
        }

        const float best  = bn * frcp_(bd);
        const float cpred = sigmoidf_(tc);
        const float m2    = pos ? 1.f : 0.01f;
        const float d     = cpred - best;
        lc = m2 * d * d;

        const float invZ = frcp_(Z);
        lk = fmaf(A2 * invZ, invZ, fmaf(-2.f * A1, invZ, A0));
    }

    // ---- block reduction ----
    for (int off = 32; off > 0; off >>= 1) {
        ll += __shfl_down(ll, off);
        lc += __shfl_down(lc, off);
        lk += __shfl_down(lk, off);
        if (COUNT_POS) np += __shfl_down(np, off);
    }
    const int wave = tid >> 6, lane = tid & 63;
    if (lane == 0) { red[wave][0]=ll; red[wave][1]=lc; red[wave][2]=lk; red[wave][3]=np; }
    __syncthreads();
    if (tid == 0) {
        float s0=0, s1=0, s2=0, s3=0;
        for (int w = 0; w < 4; ++w) { s0+=red[w][0]; s1+=red[w][1]; s2+=red[w][2]; s3+=red[w][3]; }
        atomicAdd(&acc[0], s0);
        atomicAdd(&acc[1], s1);
        atomicAdd(&acc[2], s2);
        if (COUNT_POS) atomicAdd(&acc[3], s3);
    }
}

// VW=1 block counts: S=52: BPB=32 -> 1024 blocks; S=26: BPB=8 -> 256; S=13: BPB=2 -> 64
constexpr int NBLK2 = NB * ((NA*52*52 + 255) / 256);   // 1024
constexpr int NBLK1 = NB * ((NA*26*26 + 255) / 256);   // 256
constexpr int NBLK0 = NB * ((NA*13*13 + 255) / 256);   // 64

__global__ __launch_bounds__(256) void yolo_all_kernel(
    const float* __restrict__ o0, const float* __restrict__ lo0, const float* __restrict__ c0, const float* __restrict__ bx0,
    const float* __restrict__ o1, const float* __restrict__ lo1, const float* __restrict__ c1, const float* __restrict__ bx1,
    const float* __restrict__ o2, const float* __restrict__ lo2, const float* __restrict__ c2, const float* __restrict__ bx2,
    float* __restrict__ acc)
{
    const int bid = blockIdx.x;
    if (bid < NBLK2) {
        process_scale<2, 52, false>(o2, lo2, c2, bx2, acc, bid);
    } else if (bid < NBLK2 + NBLK1) {
        process_scale<1, 26, false>(o1, lo1, c1, bx1, acc, bid - NBLK2);
    } else {
        process_scale<0, 13, true>(o0, lo0, c0, bx0, acc, bid - NBLK2 - NBLK1);
    }
}

extern "C" void kernel_launch(void* const* d_in, const int* in_sizes, int n_in,
                              void* d_out, int out_size, void* d_ws, size_t ws_size,
                              hipStream_t stream) {
    (void)in_sizes; (void)n_in; (void)out_size; (void)ws_size;
    const float* o0  = (const float*)d_in[0];
    const float* lo0 = (const float*)d_in[1];
    const float* c0  = (const float*)d_in[2];
    const float* bx0 = (const float*)d_in[3];
    const float* o1  = (const float*)d_in[4];
    const float* lo1 = (const float*)d_in[5];
    const float* c1  = (const float*)d_in[6];
    const float* bx1 = (const float*)d_in[7];
    const float* o2  = (const float*)d_in[8];
    const float* lo2 = (const float*)d_in[9];
    const float* c2  = (const float*)d_in[10];
    const float* bx2 = (const float*)d_in[11];

    float* acc = (float*)d_ws;
    float* out = (float*)d_out;

    init_acc_kernel<<<1, 64, 0, stream>>>(acc);
    yolo_all_kernel<<<NBLK2 + NBLK1 + NBLK0, 256, 0, stream>>>(
        o0, lo0, c0, bx0, o1, lo1, c1, bx1, o2, lo2, c2, bx2, acc);
    finalize_kernel<<<1, 1, 0, stream>>>(acc, out);
}